// Round 5
// baseline (348.748 us; speedup 1.0000x reference)
//
#include <hip/hip_runtime.h>

// B=4, S=2048, D=1024, H=16, Dk=64.  M = B*S = 8192.
// cvt_w(weights fp32->bf16) -> proj GEMM (fp32 A staged directly, dbuf LDS,
// q/k [bh][s][dk], v^T sigma-permuted [bh][dk][s], q pre-scaled 0.125*log2e)
// -> flash attn v4 (S^T 32x32x16, P-in-regs sigma trick, dbuf K/Vt staging)
// -> out GEMM (dbuf).  All K-loops: ONE barrier per iter, loads for tile k+1
// issued right after the barrier overlap compute of tile k.
// XCD-aware bm-fast block mapping (XCD = bm%8).  Workspace: 72 MB.

typedef __bf16 bhalf_t;
typedef __attribute__((ext_vector_type(8)))  __bf16 bf16x8;
typedef __attribute__((ext_vector_type(4)))  __bf16 bf16x4;
typedef __attribute__((ext_vector_type(4)))  float  f32x4;
typedef __attribute__((ext_vector_type(16))) float  f32x16;

typedef __attribute__((address_space(1))) void gvoid_t;
typedef __attribute__((address_space(3))) void lvoid_t;
#define GLD16(g, l) __builtin_amdgcn_global_load_lds((const gvoid_t*)(g), (lvoid_t*)(l), 16, 0, 0)

// ---------------------------------------------------------------------------
// fp32 -> bf16 for the 4 weight matrices only (4 x 1M elems)
// ---------------------------------------------------------------------------
__global__ __launch_bounds__(256) void cvt_w(
    const float* __restrict__ Wq, const float* __restrict__ Wk,
    const float* __restrict__ Wv, const float* __restrict__ Wo,
    bhalf_t* __restrict__ Wqb, bhalf_t* __restrict__ Wkb,
    bhalf_t* __restrict__ Wvb, bhalf_t* __restrict__ Wob)
{
  size_t t = (size_t)blockIdx.x * 256 + threadIdx.x;   // float4 index
  int w = (int)(t >> 18); t &= 262143;
  const float* src = (w == 0) ? Wq  : (w == 1) ? Wk  : (w == 2) ? Wv  : Wo;
  bhalf_t*     dst = (w == 0) ? Wqb : (w == 1) ? Wkb : (w == 2) ? Wvb : Wob;
  float4 f = ((const float4*)src)[t];
  bf16x4 o;
  o.x = (bhalf_t)f.x; o.y = (bhalf_t)f.y; o.z = (bhalf_t)f.z; o.w = (bhalf_t)f.w;
  ((bf16x4*)dst)[t] = o;
}

// ---------------------------------------------------------------------------
// Fused q/k/v projection.  A is fp32 (d_in), staged to LDS as fp32 via GLD16
// (XOR-swizzled 16B chunks), converted to bf16 at frag read.  B (weights) bf16.
// Double-buffered: one barrier per k-iter.  q scaled by 0.125*log2e.
// v stored transposed [bh][dk][s] with s sigma-permuted (swap bits 2<->3).
// ---------------------------------------------------------------------------
__global__ __launch_bounds__(256) void proj_gemm(
    const float* __restrict__ Qf, const float* __restrict__ Kf, const float* __restrict__ Vf,
    const bhalf_t* __restrict__ Wqb, const bhalf_t* __restrict__ Wkb, const bhalf_t* __restrict__ Wvb,
    const float* __restrict__ bq, const float* __restrict__ bk, const float* __restrict__ bv,
    bhalf_t* __restrict__ qo, bhalf_t* __restrict__ ko, bhalf_t* __restrict__ vto)
{
  __shared__ float   AsF[2][4096];   // [buf][128 rows][32 k] fp32, swizzled
  __shared__ bhalf_t Bs [2][4096];   // [buf][128 rows][32 k] bf16, swizzled

  const int seg = blockIdx.x >> 9;
  const int idx = blockIdx.x & 511;
  const int bm = idx & 63, bn = idx >> 6;    // XCD-aware: bm fast-varying

  const float *A; const bhalf_t *Bw; const float* bias; bhalf_t* out; float scale; int mode;
  if (seg == 0)      { A = Qf; Bw = Wqb; bias = bq; out = qo;  scale = 0.18033688f; mode = 0; }
  else if (seg == 1) { A = Kf; Bw = Wkb; bias = bk; out = ko;  scale = 1.0f;        mode = 0; }
  else               { A = Vf; Bw = Wvb; bias = bv; out = vto; scale = 1.0f;        mode = 1; }

  const int tid = threadIdx.x, lane = tid & 63, wave = tid >> 6;
  const int wm = wave >> 1, wn = wave & 1;
  const int quad = lane >> 4, tn = lane & 15;

  // staging lane indices
  const int ar = lane >> 3;                    // A: row within 8-row chunk
  const int ac = ((lane & 7) ^ ar) * 4;        // A: swizzled float offset
  const int br = lane >> 2;                    // B: row within 16-row chunk
  const int bc = ((lane & 3) ^ (br & 3)) * 8;  // B: swizzled bf16 offset

  const float*   Ag = A  + (size_t)(bm * 128 + ar) * 1024 + ac;
  const bhalf_t* Bg = Bw + (size_t)(bn * 128 + br) * 1024 + bc;

  auto stage = [&](int k0, int buf) {
#pragma unroll
    for (int i = 0; i < 4; ++i)
      GLD16(Ag + (size_t)(wave * 32 + i * 8) * 1024 + k0, &AsF[buf][(wave * 32 + i * 8) * 32]);
#pragma unroll
    for (int i = 0; i < 2; ++i) {
      const int c = wave * 2 + i;
      GLD16(Bg + (size_t)(c * 16) * 1024 + k0, &Bs[buf][c * 16 * 32]);
    }
  };

  f32x4 acc[4][4];
#pragma unroll
  for (int i = 0; i < 4; ++i)
#pragma unroll
    for (int j = 0; j < 4; ++j)
      acc[i][j] = (f32x4){0.f, 0.f, 0.f, 0.f};

  stage(0, 0);
  for (int k0 = 0; k0 < 1024; k0 += 32) {
    const int buf = (k0 >> 5) & 1;
    __syncthreads();                       // drains buf's loads; protects buf^1 reuse
    if (k0 + 32 < 1024) stage(k0 + 32, buf ^ 1);

    const float*   Ab = AsF[buf];
    const bhalf_t* Bb = Bs[buf];
    bf16x8 af[4], bfr[4];
#pragma unroll
    for (int i = 0; i < 4; ++i) {
      const int r = wm * 64 + i * 16 + tn;
      const int r7 = tn & 7;
      const f32x4 u0 = *(const f32x4*)(Ab + r * 32 + ((2 * quad) ^ r7) * 4);
      const f32x4 u1 = *(const f32x4*)(Ab + r * 32 + ((2 * quad + 1) ^ r7) * 4);
      bf16x8 t;
      t[0] = (bhalf_t)u0.x; t[1] = (bhalf_t)u0.y; t[2] = (bhalf_t)u0.z; t[3] = (bhalf_t)u0.w;
      t[4] = (bhalf_t)u1.x; t[5] = (bhalf_t)u1.y; t[6] = (bhalf_t)u1.z; t[7] = (bhalf_t)u1.w;
      af[i] = t;
    }
#pragma unroll
    for (int j = 0; j < 4; ++j) {
      const int r = wn * 64 + j * 16 + tn;
      bfr[j] = *(const bf16x8*)(Bb + r * 32 + (quad ^ (tn & 3)) * 8);
    }
#pragma unroll
    for (int i = 0; i < 4; ++i)
#pragma unroll
      for (int j = 0; j < 4; ++j)
        acc[i][j] = __builtin_amdgcn_mfma_f32_16x16x32_bf16(af[i], bfr[j], acc[i][j], 0, 0, 0);
  }

  // epilogue
#pragma unroll
  for (int i = 0; i < 4; ++i)
#pragma unroll
    for (int j = 0; j < 4; ++j) {
      const int n = bn * 128 + wn * 64 + j * 16 + tn;
      const float bsv = bias[n];
      const int h = n >> 6, dk = n & 63;
#pragma unroll
      for (int r = 0; r < 4; ++r) {
        const int m = bm * 128 + wm * 64 + i * 16 + quad * 4 + r;
        const int b = m >> 11, s = m & 2047;
        const float v = (acc[i][j][r] + bsv) * scale;
        size_t addr;
        if (mode == 0) addr = (((size_t)(b * 16 + h)) * 2048 + s) * 64 + dk;
        else {
          const int s2 = (s & ~12) | ((s & 4) << 1) | ((s & 8) >> 1);  // sigma
          addr = (((size_t)(b * 16 + h)) * 64 + dk) * 2048 + s2;
        }
        out[addr] = (bhalf_t)v;
      }
    }
}

// ---------------------------------------------------------------------------
// Output projection: bf16 A (attn output) @ Wo^T + bo -> fp32.  dbuf + swizzle.
// ---------------------------------------------------------------------------
__global__ __launch_bounds__(256) void out_gemm(
    const bhalf_t* __restrict__ A, const bhalf_t* __restrict__ Bw,
    const float* __restrict__ bias, float* __restrict__ Cout)
{
  __shared__ bhalf_t As[2][4096];
  __shared__ bhalf_t Bs[2][4096];
  const int bm = blockIdx.x & 63, bn = blockIdx.x >> 6;   // XCD-aware

  const int tid = threadIdx.x, lane = tid & 63, wave = tid >> 6;
  const int wm = wave >> 1, wn = wave & 1;
  const int quad = lane >> 4, tn = lane & 15;

  const int br = lane >> 2;
  const int bc = ((lane & 3) ^ (br & 3)) * 8;
  const bhalf_t* Ag = A  + (size_t)(bm * 128 + br) * 1024 + bc;
  const bhalf_t* Bg = Bw + (size_t)(bn * 128 + br) * 1024 + bc;

  auto stage = [&](int k0, int buf) {
#pragma unroll
    for (int i = 0; i < 2; ++i) {
      const int c = wave * 2 + i;
      GLD16(Ag + (size_t)(c * 16) * 1024 + k0, &As[buf][c * 16 * 32]);
      GLD16(Bg + (size_t)(c * 16) * 1024 + k0, &Bs[buf][c * 16 * 32]);
    }
  };

  f32x4 acc[4][4];
#pragma unroll
  for (int i = 0; i < 4; ++i)
#pragma unroll
    for (int j = 0; j < 4; ++j)
      acc[i][j] = (f32x4){0.f, 0.f, 0.f, 0.f};

  stage(0, 0);
  for (int k0 = 0; k0 < 1024; k0 += 32) {
    const int buf = (k0 >> 5) & 1;
    __syncthreads();
    if (k0 + 32 < 1024) stage(k0 + 32, buf ^ 1);

    const bhalf_t* Ab = As[buf];
    const bhalf_t* Bb = Bs[buf];
    bf16x8 af[4], bfr[4];
#pragma unroll
    for (int i = 0; i < 4; ++i) {
      const int r = wm * 64 + i * 16 + tn;
      af[i] = *(const bf16x8*)(Ab + r * 32 + (quad ^ (tn & 3)) * 8);
    }
#pragma unroll
    for (int j = 0; j < 4; ++j) {
      const int r = wn * 64 + j * 16 + tn;
      bfr[j] = *(const bf16x8*)(Bb + r * 32 + (quad ^ (tn & 3)) * 8);
    }
#pragma unroll
    for (int i = 0; i < 4; ++i)
#pragma unroll
      for (int j = 0; j < 4; ++j)
        acc[i][j] = __builtin_amdgcn_mfma_f32_16x16x32_bf16(af[i], bfr[j], acc[i][j], 0, 0, 0);
  }

#pragma unroll
  for (int i = 0; i < 4; ++i)
#pragma unroll
    for (int j = 0; j < 4; ++j) {
      const int n = bn * 128 + wn * 64 + j * 16 + tn;
      const float bsv = bias[n];
#pragma unroll
      for (int r = 0; r < 4; ++r) {
        const int m = bm * 128 + wm * 64 + i * 16 + quad * 4 + r;
        Cout[(size_t)m * 1024 + n] = acc[i][j][r] + bsv;
      }
    }
}

// ---------------------------------------------------------------------------
// Flash attention v4.  Block = 4 waves x 64 q rows = 256 q; kv tiles of 64.
// S^T = K @ Q^T (A=K LDS, B=Q regs).  P stays in registers (sigma-permuted V^T:
// S^T C-layout regs, exp'd+packed, ARE the PV B-fragment).  O^T = Vt @ P.
// Double-buffered K/Vt staging: one barrier per kv tile.
// ---------------------------------------------------------------------------
__global__ __launch_bounds__(256, 2) void attn_kernel(
    const bhalf_t* __restrict__ qp, const bhalf_t* __restrict__ kp,
    const bhalf_t* __restrict__ vtp, bhalf_t* __restrict__ outp)
{
  __shared__ bhalf_t Klds [2][4096];   // [buf][64 kv][64 dk], XOR-swizzled
  __shared__ bhalf_t Vtlds[2][4096];   // [buf][64 dk][64 kv(sigma)], XOR-swizzled

  const int tid = threadIdx.x, lane = tid & 63, wave = tid >> 6;
  const int q31 = lane & 31, h = lane >> 5;
  const int bh = blockIdx.y, qt = blockIdx.x;

  const bhalf_t* qbase = qp + (((size_t)bh * 2048) + qt * 256 + wave * 64 + q31) * 64;
  bf16x8 qf[2][4];
#pragma unroll
  for (int qs = 0; qs < 2; ++qs)
#pragma unroll
    for (int ks = 0; ks < 4; ++ks)
      qf[qs][ks] = *(const bf16x8*)(qbase + qs * 32 * 64 + ks * 16 + h * 8);

  f32x16 Ot[2][2];
#pragma unroll
  for (int qs = 0; qs < 2; ++qs)
#pragma unroll
    for (int dd = 0; dd < 2; ++dd)
#pragma unroll
      for (int i = 0; i < 16; ++i) Ot[qs][dd][i] = 0.f;
  float Lp[2] = {0.f, 0.f};

  const bhalf_t* kbase  = kp  + (size_t)bh * 2048 * 64;
  const bhalf_t* vtbase = vtp + (size_t)bh * 64 * 2048;

  const int rloc = lane >> 3;                 // staging row within 8-row chunk
  const int cg8  = ((lane & 7) ^ rloc) * 8;   // swizzled source chunk (elems)
  const int q7 = q31 & 7;

  auto stage = [&](int kv0, int buf) {
#pragma unroll
    for (int i = 0; i < 2; ++i) {
      const int r0 = (wave * 2 + i) * 8;
      GLD16(kbase + (size_t)(kv0 + r0 + rloc) * 64 + cg8, &Klds[buf][r0 * 64]);
      GLD16(vtbase + (size_t)(r0 + rloc) * 2048 + kv0 + cg8, &Vtlds[buf][r0 * 64]);
    }
  };

  stage(0, 0);
  for (int kv0 = 0; kv0 < 2048; kv0 += 64) {
    const int buf = (kv0 >> 6) & 1;
    __syncthreads();
    if (kv0 + 64 < 2048) stage(kv0 + 64, buf ^ 1);

    const bhalf_t* Kb  = Klds[buf];
    const bhalf_t* Vtb = Vtlds[buf];

    // S^T + exp2 + pack into PV B-fragments (register-only)
    bf16x8 pb[2][4];
#pragma unroll
    for (int mb = 0; mb < 2; ++mb) {
      bf16x8 ka[4];
#pragma unroll
      for (int ks = 0; ks < 4; ++ks)
        ka[ks] = *(const bf16x8*)(Kb + (mb * 32 + q31) * 64 + ((2 * ks + h) ^ q7) * 8);
#pragma unroll
      for (int qs = 0; qs < 2; ++qs) {
        f32x16 S;
#pragma unroll
        for (int i = 0; i < 16; ++i) S[i] = 0.f;
#pragma unroll
        for (int ks = 0; ks < 4; ++ks)
          S = __builtin_amdgcn_mfma_f32_32x32x16_bf16(ka[ks], qf[qs][ks], S, 0, 0, 0);
        float ls = 0.f;
#pragma unroll
        for (int half = 0; half < 2; ++half) {
          bf16x8 pk;
#pragma unroll
          for (int j = 0; j < 8; ++j) {
            const float e = __builtin_amdgcn_exp2f(S[half * 8 + j]);
            ls += e;
            pk[j] = (bhalf_t)e;
          }
          pb[qs][mb * 2 + half] = pk;
        }
        Lp[qs] += ls;
      }
    }

    // O^T += Vt @ P
#pragma unroll
    for (int dd = 0; dd < 2; ++dd)
#pragma unroll
      for (int kb = 0; kb < 4; ++kb) {
        const bf16x8 va = *(const bf16x8*)(Vtb + (dd * 32 + q31) * 64 + ((2 * kb + h) ^ q7) * 8);
#pragma unroll
        for (int qs = 0; qs < 2; ++qs)
          Ot[qs][dd] = __builtin_amdgcn_mfma_f32_32x32x16_bf16(va, pb[qs][kb], Ot[qs][dd], 0, 0, 0);
      }
  }

  // normalize (per-lane q) and store packed bf16x4
  const int b = bh >> 4, hh = bh & 15;
#pragma unroll
  for (int qs = 0; qs < 2; ++qs) {
    const float Lt = Lp[qs] + __shfl_xor(Lp[qs], 32, 64);
    const float linv = 1.0f / Lt;
    const int s = qt * 256 + wave * 64 + qs * 32 + q31;
    bhalf_t* ob = outp + ((size_t)(b * 2048 + s)) * 1024 + hh * 64;
#pragma unroll
    for (int dd = 0; dd < 2; ++dd)
#pragma unroll
      for (int g = 0; g < 4; ++g) {
        bf16x4 o;
        o.x = (bhalf_t)(Ot[qs][dd][4 * g + 0] * linv);
        o.y = (bhalf_t)(Ot[qs][dd][4 * g + 1] * linv);
        o.z = (bhalf_t)(Ot[qs][dd][4 * g + 2] * linv);
        o.w = (bhalf_t)(Ot[qs][dd][4 * g + 3] * linv);
        *(bf16x4*)(ob + dd * 32 + g * 8 + h * 4) = o;
      }
  }
}

// ---------------------------------------------------------------------------
extern "C" void kernel_launch(void* const* d_in, const int* in_sizes, int n_in,
                              void* d_out, int out_size, void* d_ws, size_t ws_size,
                              hipStream_t stream)
{
  const float* Q  = (const float*)d_in[0];
  const float* K  = (const float*)d_in[1];
  const float* V  = (const float*)d_in[2];
  const float* Wq = (const float*)d_in[3];
  const float* bq = (const float*)d_in[4];
  const float* Wk = (const float*)d_in[5];
  const float* bk = (const float*)d_in[6];
  const float* Wv = (const float*)d_in[7];
  const float* bv = (const float*)d_in[8];
  const float* Wo = (const float*)d_in[9];
  const float* bo = (const float*)d_in[10];

  char* ws = (char*)d_ws;
  const size_t SZ = 8192ull * 1024 * 2;   // 16 MB  [8192,1024] bf16
  const size_t WZ = 1024ull * 1024 * 2;   //  2 MB  [1024,1024] bf16
  bhalf_t* Wqb    = (bhalf_t*)(ws);
  bhalf_t* Wkb    = (bhalf_t*)(ws + WZ);
  bhalf_t* Wvb    = (bhalf_t*)(ws + 2 * WZ);
  bhalf_t* Wob    = (bhalf_t*)(ws + 3 * WZ);
  bhalf_t* q_p    = (bhalf_t*)(ws + 4 * WZ);
  bhalf_t* k_p    = (bhalf_t*)(ws + 4 * WZ + SZ);
  bhalf_t* vt_p   = (bhalf_t*)(ws + 4 * WZ + 2 * SZ);
  bhalf_t* attn_o = (bhalf_t*)(ws + 4 * WZ + 3 * SZ);

  cvt_w<<<4096, 256, 0, stream>>>(Wq, Wk, Wv, Wo, Wqb, Wkb, Wvb, Wob);
  proj_gemm<<<1536, 256, 0, stream>>>(Q, K, V, Wqb, Wkb, Wvb,
                                      bq, bk, bv, q_p, k_p, vt_p);
  attn_kernel<<<dim3(8, 64), 256, 0, stream>>>(q_p, k_p, vt_p, attn_o);
  out_gemm<<<512, 256, 0, stream>>>(attn_o, Wob, bo, (float*)d_out);
}